// Round 8
// baseline (200.271 us; speedup 1.0000x reference)
//
#include <hip/hip_runtime.h>
#include <hip/hip_fp16.h>
#include <math.h>

#define SEQ    1024
#define DK     16
#define NHEAD  16
#define NBATCH 8
#define LOG2E  1.4426950408889634f

#define CH     64                        // keys per LDS chunk
#define NCH    (SEQ / CH)                // 16 chunks
#define KHL_STRIDE 72                    // LDS bytes per key row (64 data + 8 pad)
#define VT_STRIDE  144                   // LDS bytes per d row   (128 data + 16 pad)
#define KHL_CH (CH * KHL_STRIDE)         // 4608 B
#define VT_CH  (DK * VT_STRIDE)          // 2304 B
#define BUF_SZ (KHL_CH + VT_CH)          // 6912 B per buffer (x2 = 13.5 KB)

typedef __attribute__((ext_vector_type(4))) short  short4v;
typedef __attribute__((ext_vector_type(2))) short  short2v;
typedef __attribute__((ext_vector_type(4))) float  float4v;
typedef __attribute__((ext_vector_type(2))) unsigned int uint2v;

static __device__ __forceinline__ float fast_exp2(float x) {
#if __has_builtin(__builtin_amdgcn_exp2f)
    return __builtin_amdgcn_exp2f(x);
#else
    return exp2f(x);
#endif
}

static __device__ __forceinline__ float4v mfma16(short4v a, short4v b, float4v c) {
#if __has_builtin(__builtin_amdgcn_mfma_f32_16x16x16bf16_1k)
    return __builtin_amdgcn_mfma_f32_16x16x16bf16_1k(a, b, c, 0, 0, 0);
#else
    float4v d = c;
    asm volatile("v_mfma_f32_16x16x16_bf16 %0, %1, %2, %0" : "+v"(d) : "v"(a), "v"(b));
    return d;
#endif
}

static __device__ __forceinline__ unsigned bf16_rne(float x) {
    unsigned u = __float_as_uint(x);
    return (u + 0x7FFFu + ((u >> 16) & 1u)) >> 16;
}
static __device__ __forceinline__ float bf16_to_f(unsigned b) {
    return __uint_as_float(b << 16);
}
static __device__ __forceinline__ unsigned pk_bf16(float a, float b) {
#if __has_builtin(__builtin_amdgcn_cvt_pk_bf16_f32)
    short2v r = __builtin_amdgcn_cvt_pk_bf16_f32(a, b);
    return __builtin_bit_cast(unsigned, r);
#else
    return bf16_rne(a) | (bf16_rne(b) << 16);
#endif
}
static __device__ __forceinline__ short4v bc_s4(unsigned lo, unsigned hi) {
    uint2v u; u.x = lo; u.y = hi;
    return __builtin_bit_cast(short4v, u);
}
static __device__ __forceinline__ unsigned h2pack(int m0, float b0, int m1, float b1) {
    const __half2 a = __floats2half2_rn(m0 ? -60000.f : b0 * LOG2E,
                                        m1 ? -60000.f : b1 * LOG2E);
    return __builtin_bit_cast(unsigned, a);
}

// ---------------- Prep (one kernel, 3 jobs by block range) -------------------
// [0,2048):     K -> KHL: per key row, 4 x [hi d4 | lo d4] 16B blocks
// [2048,4096):  V -> Vt bf16 [B*H][d][s]
// [4096,6144):  bias+mask -> biasp fp16 fragment-major
__global__ __launch_bounds__(256)
void prep_all(const float* __restrict__ K, const float* __restrict__ V,
              const int* __restrict__ mask, const float* __restrict__ bias,
              uint4* __restrict__ KHL, short* __restrict__ Vt,
              uint4* __restrict__ biasp) {
    const int blk = blockIdx.x;
    if (blk < 2048) {
        const int i4 = blk * 256 + threadIdx.x;          // float4 index into K
        const float4 k = ((const float4*)K)[i4];
        const float w[4] = {k.x, k.y, k.z, k.w};
        uint4 o;
        o.x = pk_bf16(w[0], w[1]);
        o.y = pk_bf16(w[2], w[3]);
        o.z = pk_bf16(w[0] - bf16_to_f(o.x & 0xFFFFu), w[1] - bf16_to_f(o.x >> 16));
        o.w = pk_bf16(w[2] - bf16_to_f(o.y & 0xFFFFu), w[3] - bf16_to_f(o.y >> 16));
        KHL[i4] = o;
    } else if (blk < 4096) {
        __shared__ float Vs[64][17];
        const int t  = threadIdx.x;
        const int bb = blk - 2048;
        const int bh = bb >> 4;
        const int s0 = (bb & 15) * 64;
        {
            const int row = t >> 2, c4 = t & 3;
            const float4 v = ((const float4*)V)[((size_t)bh * SEQ + s0 + row) * 4 + c4];
            Vs[row][c4 * 4 + 0] = v.x; Vs[row][c4 * 4 + 1] = v.y;
            Vs[row][c4 * 4 + 2] = v.z; Vs[row][c4 * 4 + 3] = v.w;
        }
        __syncthreads();
        const int d = t >> 4, sg = t & 15;
        short4v o;
        #pragma unroll
        for (int i = 0; i < 4; ++i) o[i] = (short)bf16_rne(Vs[sg * 4 + i][d]);
        ((short4v*)Vt)[(((size_t)bh * DK + d) * SEQ + s0) / 4 + sg] = o;
    } else {
        // bias transpose: block = (b, qt64, c128, half) handles 64 q x 64 k
        __shared__ uint4 BsT[64][9];
        const int t    = threadIdx.x;
        const int blk2 = blk - 4096;
        const int b    = blk2 >> 8;
        const int qt64 = (blk2 >> 4) & 15;
        const int c    = (blk2 >> 1) & 7;
        const int half = blk2 & 1;
        const int kb   = c * 128 + half * 64;

        #pragma unroll
        for (int i = 0; i < 4; ++i) {
            const int idx = t + i * 256;
            const int row = idx >> 4;                    // q-local 0..63
            const int c4  = idx & 15;                    // float4 col in 64-k window
            const size_t ga = ((size_t)b * SEQ + qt64 * 64 + row) * SEQ + kb + c4 * 4;
            const float4 bv = *(const float4*)(bias + ga);
            const int4   mv = *(const int4*)(mask + ga);
            uint2 u;
            u.x = h2pack(mv.x, bv.x, mv.y, bv.y);
            u.y = h2pack(mv.z, bv.z, mv.w, bv.w);
            const int j = c4 >> 1;
            ((uint2*)&BsT[row][j ^ (row & 7)])[c4 & 1] = u;
        }
        __syncthreads();
        const int w = t >> 6, lane = t & 63, n = lane & 15, g = lane >> 4;
        const int row = w * 16 + n;
        #pragma unroll
        for (int tpl = 0; tpl < 2; ++tpl) {
            const int tp = half * 2 + tpl;
            const int jj = tpl * 4 + g;
            const uint4 v = BsT[row][jj ^ (row & 7)];
            const size_t ob = ((((size_t)(b * 16 + qt64) * 4 + w) * 8 + c) * 4 + tp) * 64 + lane;
            biasp[ob] = v;
        }
    }
}

// ---------------- Flash pass ------------------------------------------------
// 2048 blocks = 8 b x 16 qt64 x 16 h, blockIdx%8 == b (XCD = batch):
// 8 blocks/CU, 32 waves/CU. Block = one 64-q tile; wave = 16 q rows.
// K/V from pre-converted ws, 64-key chunks double-buffered in LDS.
// l computed by ones-MFMA in the matrix pipe (no VALU adds, no shuffles).
__global__ __launch_bounds__(256, 8)
void sdpa_flash(const float* __restrict__ Q, const uint4* __restrict__ KHL,
                const short* __restrict__ Vt, const uint4* __restrict__ biasp,
                float* __restrict__ out) {
    __shared__ __align__(16) char smem[2][BUF_SZ];

    const int tid  = threadIdx.x;
    const int wave = tid >> 6;
    const int lane = tid & 63;
    const int n    = lane & 15;
    const int g    = lane >> 4;
    const int permn = ((n >> 2) << 3) | (n & 3);   // tile-pair key permutation

    const int b  = blockIdx.x & 7;                 // XCD = batch
    const int j  = blockIdx.x >> 3;                // 0..255
    const int qt = j & 15;                         // 64-q tile
    const int h  = j >> 4;                         // 0..15
    const int q0 = qt * 64;

    const size_t bh   = (size_t)b * NHEAD + h;
    const int    qrow = q0 + wave * 16 + n;

    // Q -> scaled bf16 hi/lo frag
    short4v qh, ql;
    {
        const float4 qv = *(const float4*)(Q + (bh * SEQ + qrow) * DK + g * 4);
        const float qsc = 0.25f * LOG2E;
        const float v[4] = {qv.x * qsc, qv.y * qsc, qv.z * qsc, qv.w * qsc};
        #pragma unroll
        for (int e = 0; e < 4; ++e) {
            const unsigned hu = bf16_rne(v[e]);
            qh[e] = (short)hu;
            ql[e] = (short)bf16_rne(v[e] - bf16_to_f(hu));
        }
    }
    const size_t bfbase = (((size_t)(b * 16 + qt) * 4 + wave) * 32) * 64 + lane;

    const uint4* KHLh = KHL + bh * SEQ * 4;        // 4 uint4 per key row
    const uint4* VtH  = (const uint4*)(Vt + bh * DK * SEQ);  // 128 uint4 per d row

    const int vd = tid >> 3, vc = tid & 7;         // V staging coords (tid<128)

    float4v acc   = (float4v){0.f, 0.f, 0.f, 0.f};
    float4v acc_l = (float4v){0.f, 0.f, 0.f, 0.f};
    const short4v kOnes = {(short)0x3F80, (short)0x3F80, (short)0x3F80, (short)0x3F80};

    uint4 kst, vst;
    kst = KHLh[tid];
    if (tid < 128) vst = VtH[vd * 128 + vc];

    auto stage = [&](char* s) {
        *(uint4*)(s + (tid >> 2) * KHL_STRIDE + (tid & 3) * 16) = kst;
        if (tid < 128)
            *(uint4*)(s + KHL_CH + vd * VT_STRIDE + vc * 16) = vst;
    };

    stage(smem[0]);
    __syncthreads();

    for (int c = 0; c < NCH; ++c) {
        const int cur = c & 1;
        if (c < NCH - 1) {
            kst = KHLh[(c + 1) * 256 + tid];
            if (tid < 128) vst = VtH[vd * 128 + (c + 1) * 8 + vc];
        }
        uint4 bb[2];
        bb[0] = biasp[bfbase + (size_t)(c * 2 + 0) * 64];
        bb[1] = biasp[bfbase + (size_t)(c * 2 + 1) * 64];

        const char* khl = smem[cur];
        const char* vtl = smem[cur] + KHL_CH;

        #pragma unroll
        for (int tp = 0; tp < 2; ++tp) {
            const int rowA = tp * 32 + permn;
            const uint4 kA = *(const uint4*)(khl + rowA * KHL_STRIDE + g * 16);
            const uint4 kB = *(const uint4*)(khl + (rowA + 4) * KHL_STRIDE + g * 16);
            const uint4 vv = *(const uint4*)(vtl + n * VT_STRIDE + tp * 64 + g * 16);
            const short4v khiA = bc_s4(kA.x, kA.y), kloA = bc_s4(kA.z, kA.w);
            const short4v khiB = bc_s4(kB.x, kB.y), kloB = bc_s4(kB.z, kB.w);
            const short4v vtA  = bc_s4(vv.x, vv.y), vtB  = bc_s4(vv.z, vv.w);

            {   // tile A: keys c*64 + tp*32 + 8g + r
                const float2 f01 = __half22float2(__builtin_bit_cast(__half2, bb[tp].x));
                const float2 f23 = __half22float2(__builtin_bit_cast(__half2, bb[tp].y));
                float4v s; s[0] = f01.x; s[1] = f01.y; s[2] = f23.x; s[3] = f23.y;
                s = mfma16(khiA, qh, s);
                s = mfma16(kloA, qh, s);
                s = mfma16(khiA, ql, s);
                const float p0 = fast_exp2(s[0]), p1 = fast_exp2(s[1]);
                const float p2 = fast_exp2(s[2]), p3 = fast_exp2(s[3]);
                const short4v pf = bc_s4(pk_bf16(p0, p1), pk_bf16(p2, p3));
                acc   = mfma16(pf, vtA,   acc);
                acc_l = mfma16(pf, kOnes, acc_l);
            }
            {   // tile B: keys c*64 + tp*32 + 8g + 4 + r
                const float2 f01 = __half22float2(__builtin_bit_cast(__half2, bb[tp].z));
                const float2 f23 = __half22float2(__builtin_bit_cast(__half2, bb[tp].w));
                float4v s; s[0] = f01.x; s[1] = f01.y; s[2] = f23.x; s[3] = f23.y;
                s = mfma16(khiB, qh, s);
                s = mfma16(kloB, qh, s);
                s = mfma16(khiB, ql, s);
                const float p0 = fast_exp2(s[0]), p1 = fast_exp2(s[1]);
                const float p2 = fast_exp2(s[2]), p3 = fast_exp2(s[3]);
                const short4v pf = bc_s4(pk_bf16(p0, p1), pk_bf16(p2, p3));
                acc   = mfma16(pf, vtB,   acc);
                acc_l = mfma16(pf, kOnes, acc_l);
            }
        }

        if (c < NCH - 1) stage(smem[cur ^ 1]);
        __syncthreads();
    }

    // epilogue: acc_l[r] == l for q-row 4g+r (summed over all keys)
    const size_t obase = bh * SEQ + q0 + wave * 16;
    #pragma unroll
    for (int r = 0; r < 4; ++r) {
        const float inv = 1.0f / acc_l[r];
        out[(obase + 4 * g + r) * DK + n] = acc[r] * inv;
    }
}

// ---------------- Fallback: single-pass scalar kernel (no workspace) ---------
#define FTQ 256
#define FTK 32
__global__ __launch_bounds__(256, 2)
void sdpa_fallback(const float* __restrict__ Q, const float* __restrict__ K,
                   const float* __restrict__ V, const int* __restrict__ mask,
                   const float* __restrict__ bias, float* __restrict__ out) {
    __shared__ float Ks[FTK][DK];
    __shared__ float Vs[FTK][DK];
    __shared__ float Bsf[FTQ][FTK + 1];

    const int tid = threadIdx.x;
    const int blk = blockIdx.x;
    const int h   = blk & (NHEAD - 1);
    const int qt  = (blk >> 4) & 3;
    const int b   = blk >> 6;
    const int q0  = qt * FTQ;
    const float qscale = 0.25f * LOG2E;
    const size_t bh = (size_t)b * NHEAD + h;

    float Qr[DK];
    {
        const float4* q4 = (const float4*)(Q + (bh * SEQ + q0 + tid) * DK);
        #pragma unroll
        for (int i = 0; i < 4; ++i) {
            float4 v = q4[i];
            Qr[4*i+0] = v.x * qscale; Qr[4*i+1] = v.y * qscale;
            Qr[4*i+2] = v.z * qscale; Qr[4*i+3] = v.w * qscale;
        }
    }
    float acc[DK];
    #pragma unroll
    for (int d = 0; d < DK; ++d) acc[d] = 0.0f;
    float l = 0.0f;

    const float* Kbase = K + bh * SEQ * DK;
    const float* Vbase = V + bh * SEQ * DK;
    const float* Bbase = bias + ((size_t)b * SEQ + q0) * SEQ;
    const int*   Mbase = mask + ((size_t)b * SEQ + q0) * SEQ;

    for (int t = 0; t < SEQ / FTK; ++t) {
        const int k0 = t * FTK;
        if (tid < 128) {
            float4 kv = ((const float4*)(Kbase + (size_t)k0 * DK))[tid];
            float4 vv = ((const float4*)(Vbase + (size_t)k0 * DK))[tid];
            ((float4*)&Ks[0][0])[tid] = kv;
            ((float4*)&Vs[0][0])[tid] = vv;
        }
        #pragma unroll
        for (int i = 0; i < 8; ++i) {
            int e4 = tid + i * 256, row = e4 >> 3, c4 = e4 & 7;
            const float4 bv = *(const float4*)(Bbase + (size_t)row * SEQ + k0 + c4 * 4);
            const int4   mv = *(const int4*)  (Mbase + (size_t)row * SEQ + k0 + c4 * 4);
            float* dst = &Bsf[row][c4 * 4];
            dst[0] = mv.x ? -1e9f : bv.x * LOG2E;
            dst[1] = mv.y ? -1e9f : bv.y * LOG2E;
            dst[2] = mv.z ? -1e9f : bv.z * LOG2E;
            dst[3] = mv.w ? -1e9f : bv.w * LOG2E;
        }
        __syncthreads();
        #pragma unroll 4
        for (int kk = 0; kk < FTK; ++kk) {
            float s = Bsf[tid][kk];
            const float4 k0v = *(const float4*)&Ks[kk][0];
            const float4 k1v = *(const float4*)&Ks[kk][4];
            const float4 k2v = *(const float4*)&Ks[kk][8];
            const float4 k3v = *(const float4*)&Ks[kk][12];
            s = fmaf(Qr[0],  k0v.x, s); s = fmaf(Qr[1],  k0v.y, s);
            s = fmaf(Qr[2],  k0v.z, s); s = fmaf(Qr[3],  k0v.w, s);
            s = fmaf(Qr[4],  k1v.x, s); s = fmaf(Qr[5],  k1v.y, s);
            s = fmaf(Qr[6],  k1v.z, s); s = fmaf(Qr[7],  k1v.w, s);
            s = fmaf(Qr[8],  k2v.x, s); s = fmaf(Qr[9],  k2v.y, s);
            s = fmaf(Qr[10], k2v.z, s); s = fmaf(Qr[11], k2v.w, s);
            s = fmaf(Qr[12], k3v.x, s); s = fmaf(Qr[13], k3v.y, s);
            s = fmaf(Qr[14], k3v.z, s); s = fmaf(Qr[15], k3v.w, s);
            float p = fast_exp2(s);
            l += p;
            const float4 v0 = *(const float4*)&Vs[kk][0];
            const float4 v1 = *(const float4*)&Vs[kk][4];
            const float4 v2 = *(const float4*)&Vs[kk][8];
            const float4 v3 = *(const float4*)&Vs[kk][12];
            acc[0]  = fmaf(p, v0.x, acc[0]);  acc[1]  = fmaf(p, v0.y, acc[1]);
            acc[2]  = fmaf(p, v0.z, acc[2]);  acc[3]  = fmaf(p, v0.w, acc[3]);
            acc[4]  = fmaf(p, v1.x, acc[4]);  acc[5]  = fmaf(p, v1.y, acc[5]);
            acc[6]  = fmaf(p, v1.z, acc[6]);  acc[7]  = fmaf(p, v1.w, acc[7]);
            acc[8]  = fmaf(p, v2.x, acc[8]);  acc[9]  = fmaf(p, v2.y, acc[9]);
            acc[10] = fmaf(p, v2.z, acc[10]); acc[11] = fmaf(p, v2.w, acc[11]);
            acc[12] = fmaf(p, v3.x, acc[12]); acc[13] = fmaf(p, v3.y, acc[13]);
            acc[14] = fmaf(p, v3.z, acc[14]); acc[15] = fmaf(p, v3.w, acc[15]);
        }
        __syncthreads();
    }
    const float inv = 1.0f / l;
    float4* o4 = (float4*)(out + (bh * SEQ + q0 + tid) * DK);
    #pragma unroll
    for (int i = 0; i < 4; ++i) {
        float4 v;
        v.x = acc[4*i+0] * inv; v.y = acc[4*i+1] * inv;
        v.z = acc[4*i+2] * inv; v.w = acc[4*i+3] * inv;
        o4[i] = v;
    }
}

extern "C" void kernel_launch(void* const* d_in, const int* in_sizes, int n_in,
                              void* d_out, int out_size, void* d_ws, size_t ws_size,
                              hipStream_t stream) {
    const float* Q    = (const float*)d_in[0];
    const float* K    = (const float*)d_in[1];
    const float* V    = (const float*)d_in[2];
    const int*   mask = (const int*)  d_in[3];
    const float* bias = (const float*)d_in[4];
    float* out = (float*)d_out;

    const size_t nKeys    = (size_t)NBATCH * NHEAD * SEQ;      // 131072
    const size_t khlBytes = nKeys * 64;                        // 8.39 MB
    const size_t vtBytes  = nKeys * DK * sizeof(short);        // 4.19 MB
    const size_t bpBytes  = (size_t)NBATCH * SEQ * SEQ * 2;    // 16.8 MB
    const size_t need     = khlBytes + vtBytes + bpBytes;      // 29.4 MB

    if (ws_size >= need) {
        char* w = (char*)d_ws;
        uint4* KHL   = (uint4*)(w);
        short* Vt    = (short*)(w + khlBytes);
        uint4* biasp = (uint4*)(w + khlBytes + vtBytes);

        prep_all<<<6144, 256, 0, stream>>>(K, V, mask, bias, KHL, Vt, biasp);
        sdpa_flash<<<2048, 256, 0, stream>>>(Q, KHL, Vt, biasp, out);
    } else {
        sdpa_fallback<<<NBATCH * NHEAD * (SEQ / FTQ), FTQ, 0, stream>>>(Q, K, V, mask, bias, out);
    }
}

// Round 9
// 167.212 us; speedup vs baseline: 1.1977x; 1.1977x over previous
//
#include <hip/hip_runtime.h>
#include <hip/hip_fp16.h>
#include <math.h>

#define SEQ    1024
#define DK     16
#define NHEAD  16
#define NBATCH 8
#define LOG2E  1.4426950408889634f

#define CH     128                       // keys per LDS chunk
#define NCH    (SEQ / CH)                // 8 chunks
#define KHL_STRIDE 72                    // LDS bytes per key row (64 data + 8 pad)
#define VT_STRIDE  272                   // LDS bytes per d row   (256 data + 16 pad)
#define KHL_CH (CH * KHL_STRIDE)         // 9216 B
#define VT_CH  (DK * VT_STRIDE)          // 4352 B
#define BUF_SZ (KHL_CH + VT_CH)          // 13568 B per buffer (x2 = 26.5 KB)

typedef __attribute__((ext_vector_type(4))) short  short4v;
typedef __attribute__((ext_vector_type(8))) short  short8v;
typedef __attribute__((ext_vector_type(2))) short  short2v;
typedef __attribute__((ext_vector_type(4))) float  float4v;
typedef __attribute__((ext_vector_type(2))) unsigned int uint2v;

static __device__ __forceinline__ float fast_exp2(float x) {
#if __has_builtin(__builtin_amdgcn_exp2f)
    return __builtin_amdgcn_exp2f(x);
#else
    return exp2f(x);
#endif
}

static __device__ __forceinline__ float4v mfma16(short4v a, short4v b, float4v c) {
#if __has_builtin(__builtin_amdgcn_mfma_f32_16x16x16bf16_1k)
    return __builtin_amdgcn_mfma_f32_16x16x16bf16_1k(a, b, c, 0, 0, 0);
#else
    float4v d = c;
    asm volatile("v_mfma_f32_16x16x16_bf16 %0, %1, %2, %0" : "+v"(d) : "v"(a), "v"(b));
    return d;
#endif
}

// K=32 MFMA: A/B = 8 bf16/lane (k = quad*8 + j). Fallback: two K=16 halves
// (identical semantics — the k-sum is just partitioned).
static __device__ __forceinline__ float4v mfma32(short8v a, short8v b, float4v c) {
#if __has_builtin(__builtin_amdgcn_mfma_f32_16x16x32_bf16)
    return __builtin_amdgcn_mfma_f32_16x16x32_bf16(a, b, c, 0, 0, 0);
#else
    short4v a0 = {a[0], a[1], a[2], a[3]}, a1 = {a[4], a[5], a[6], a[7]};
    short4v b0 = {b[0], b[1], b[2], b[3]}, b1 = {b[4], b[5], b[6], b[7]};
    c = mfma16(a0, b0, c);
    return mfma16(a1, b1, c);
#endif
}

static __device__ __forceinline__ unsigned bf16_rne(float x) {
    unsigned u = __float_as_uint(x);
    return (u + 0x7FFFu + ((u >> 16) & 1u)) >> 16;
}
static __device__ __forceinline__ float bf16_to_f(unsigned b) {
    return __uint_as_float(b << 16);
}
static __device__ __forceinline__ unsigned pk_bf16(float a, float b) {
#if __has_builtin(__builtin_amdgcn_cvt_pk_bf16_f32)
    short2v r = __builtin_amdgcn_cvt_pk_bf16_f32(a, b);
    return __builtin_bit_cast(unsigned, r);
#else
    return bf16_rne(a) | (bf16_rne(b) << 16);
#endif
}
static __device__ __forceinline__ short4v bc_s4(unsigned lo, unsigned hi) {
    uint2v u; u.x = lo; u.y = hi;
    return __builtin_bit_cast(short4v, u);
}
static __device__ __forceinline__ unsigned h2pack(int m0, float b0, int m1, float b1) {
    const __half2 a = __floats2half2_rn(m0 ? -60000.f : b0 * LOG2E,
                                        m1 ? -60000.f : b1 * LOG2E);
    return __builtin_bit_cast(unsigned, a);
}

// ---------------- Prep (one kernel, 3 jobs by block range) -------------------
// [0,2048):     bias+mask -> biasp fp16 fragment-major (64q x 64k per block)
// [2048,2560):  K -> KHL: per key row, 4 x [hi d4 | lo d4] 16B blocks
// [2560,3072):  V -> Vt bf16 [B*H][d][s]
__global__ __launch_bounds__(256)
void prep_all(const float* __restrict__ K, const float* __restrict__ V,
              const int* __restrict__ mask, const float* __restrict__ bias,
              uint4* __restrict__ KHL, short* __restrict__ Vt,
              uint4* __restrict__ biasp) {
    const int blk = blockIdx.x;
    const int t   = threadIdx.x;
    if (blk < 2048) {
        __shared__ uint4 BsT[64][9];
        const int b    = blk >> 8;
        const int qt64 = (blk >> 4) & 15;
        const int c    = (blk >> 1) & 7;
        const int half = blk & 1;
        const int kb   = c * 128 + half * 64;
        #pragma unroll
        for (int i = 0; i < 4; ++i) {
            const int idx = t + i * 256;                 // 0..1023
            const int row = idx >> 4;                    // q-local 0..63
            const int c4  = idx & 15;                    // float4 col in 64-k window
            const size_t ga = ((size_t)b * SEQ + qt64 * 64 + row) * SEQ + kb + c4 * 4;
            const float4 bv = *(const float4*)(bias + ga);
            const int4   mv = *(const int4*)(mask + ga);
            uint2 u;
            u.x = h2pack(mv.x, bv.x, mv.y, bv.y);
            u.y = h2pack(mv.z, bv.z, mv.w, bv.w);
            const int jj = c4 >> 1;
            ((uint2*)&BsT[row][jj ^ (row & 7)])[c4 & 1] = u;
        }
        __syncthreads();
        const int w = t >> 6, lane = t & 63, n = lane & 15, g = lane >> 4;
        const int row = w * 16 + n;
        #pragma unroll
        for (int tpl = 0; tpl < 2; ++tpl) {
            const int tp = half * 2 + tpl;
            const int jj = tpl * 4 + g;
            const uint4 v = BsT[row][jj ^ (row & 7)];
            const size_t ob = ((((size_t)(b * 16 + qt64) * 4 + w) * 8 + c) * 4 + tp) * 64 + lane;
            biasp[ob] = v;
        }
    } else if (blk < 2560) {
        const int base = (blk - 2048) * 1024;
        #pragma unroll
        for (int i = 0; i < 4; ++i) {
            const int i4 = base + t + i * 256;           // float4 index into K
            const float4 k = ((const float4*)K)[i4];
            const float w[4] = {k.x, k.y, k.z, k.w};
            uint4 o;
            o.x = pk_bf16(w[0], w[1]);
            o.y = pk_bf16(w[2], w[3]);
            o.z = pk_bf16(w[0] - bf16_to_f(o.x & 0xFFFFu), w[1] - bf16_to_f(o.x >> 16));
            o.w = pk_bf16(w[2] - bf16_to_f(o.y & 0xFFFFu), w[3] - bf16_to_f(o.y >> 16));
            KHL[i4] = o;
        }
    } else {
        __shared__ float Vs[64][17];
        const int vb = blk - 2560;                       // 0..511
        const int bh = vb >> 2;
        const int qq = vb & 3;
        #pragma unroll
        for (int st = 0; st < 4; ++st) {
            const int s0 = qq * 256 + st * 64;
            {
                const int row = t >> 2, c4 = t & 3;
                const float4 v = ((const float4*)V)[((size_t)bh * SEQ + s0 + row) * 4 + c4];
                Vs[row][c4 * 4 + 0] = v.x; Vs[row][c4 * 4 + 1] = v.y;
                Vs[row][c4 * 4 + 2] = v.z; Vs[row][c4 * 4 + 3] = v.w;
            }
            __syncthreads();
            const int d = t >> 4, sg = t & 15;
            short4v o;
            #pragma unroll
            for (int i = 0; i < 4; ++i) o[i] = (short)bf16_rne(Vs[sg * 4 + i][d]);
            ((short4v*)Vt)[(((size_t)bh * DK + d) * SEQ + s0) / 4 + sg] = o;
            __syncthreads();
        }
    }
}

// ---------------- Flash pass (R6 structure + K=32 PV/l fusion) ---------------
// 1024 blocks, blockIdx%8 == b (XCD = batch), 128 q/block, 2 frags/wave,
// CH=128 double-buffered LDS. Per tile-pair: 6 QK MFMA(K=16) + 1 PV MFMA(K=32)
// + 1 ones-l MFMA(K=32); l comes out in C-layout -> epilogue has no shuffles.
__global__ __launch_bounds__(256, 4)
void sdpa_flash(const float* __restrict__ Q, const uint4* __restrict__ KHL,
                const short* __restrict__ Vt, const uint4* __restrict__ biasp,
                float* __restrict__ out) {
    __shared__ __align__(16) char smem[2][BUF_SZ];

    const int tid  = threadIdx.x;
    const int wave = tid >> 6;
    const int lane = tid & 63;
    const int n    = lane & 15;
    const int g    = lane >> 4;
    const int permn = ((n >> 2) << 3) | (n & 3);   // tile-pair key permutation

    const int b  = blockIdx.x & 7;                 // XCD = batch
    const int j  = blockIdx.x >> 3;                // 0..127
    const int qt = j & 7;
    const int h  = j >> 3;                         // 0..15
    const int q0 = qt * 128;

    const size_t bh = (size_t)b * NHEAD + h;

    // 2 q-frags: q = q0 + f*64 + wave*16 + n
    short4v qh[2], ql[2];
    size_t  bfbase[2];
    #pragma unroll
    for (int f = 0; f < 2; ++f) {
        const int qrow = q0 + f * 64 + wave * 16 + n;
        const float4 qv = *(const float4*)(Q + (bh * SEQ + qrow) * DK + g * 4);
        const float qsc = 0.25f * LOG2E;
        const float v[4] = {qv.x * qsc, qv.y * qsc, qv.z * qsc, qv.w * qsc};
        #pragma unroll
        for (int e = 0; e < 4; ++e) {
            const unsigned hu = bf16_rne(v[e]);
            qh[f][e] = (short)hu;
            ql[f][e] = (short)bf16_rne(v[e] - bf16_to_f(hu));
        }
        bfbase[f] = (((size_t)(b * 16 + qt * 2 + f) * 4 + wave) * 32) * 64 + lane;
    }

    const uint4* KHLh = KHL + bh * SEQ * 4;              // 4 uint4 per key row
    const uint4* VtH  = (const uint4*)(Vt + bh * DK * SEQ);

    float4v acc[2], accl[2];
    acc[0]  = (float4v){0.f, 0.f, 0.f, 0.f};
    acc[1]  = (float4v){0.f, 0.f, 0.f, 0.f};
    accl[0] = (float4v){0.f, 0.f, 0.f, 0.f};
    accl[1] = (float4v){0.f, 0.f, 0.f, 0.f};
    const short8v ones8 = {(short)0x3F80, (short)0x3F80, (short)0x3F80, (short)0x3F80,
                           (short)0x3F80, (short)0x3F80, (short)0x3F80, (short)0x3F80};

    uint4 st0, st1, st2;
    {
        st0 = KHLh[tid];
        st1 = KHLh[256 + tid];
        st2 = VtH[(tid >> 4) * 128 + (tid & 15)];
        char* s = smem[0];
        *(uint4*)(s + (tid >> 2) * KHL_STRIDE + (tid & 3) * 16) = st0;
        const int e = tid + 256;
        *(uint4*)(s + (e >> 2) * KHL_STRIDE + (e & 3) * 16) = st1;
        *(uint4*)(s + KHL_CH + (tid >> 4) * VT_STRIDE + (tid & 15) * 16) = st2;
    }
    __syncthreads();

    for (int c = 0; c < NCH; ++c) {
        const int cur = c & 1;
        if (c < NCH - 1) {
            const uint4* kg = KHLh + (c + 1) * 512;
            st0 = kg[tid];
            st1 = kg[256 + tid];
            st2 = VtH[(tid >> 4) * 128 + (c + 1) * 16 + (tid & 15)];
        }
        uint4 bb[2][4];
        #pragma unroll
        for (int f = 0; f < 2; ++f)
            #pragma unroll
            for (int tp = 0; tp < 4; ++tp)
                bb[f][tp] = biasp[bfbase[f] + (size_t)(c * 4 + tp) * 64];

        const char* khl = smem[cur];
        const char* vtl = smem[cur] + KHL_CH;

        #pragma unroll
        for (int tp = 0; tp < 4; ++tp) {
            const int rowA = tp * 32 + permn;
            const uint4 kA = *(const uint4*)(khl + rowA * KHL_STRIDE + g * 16);
            const uint4 kB = *(const uint4*)(khl + (rowA + 4) * KHL_STRIDE + g * 16);
            const uint4 vv = *(const uint4*)(vtl + n * VT_STRIDE + tp * 64 + g * 16);
            const short4v khiA = bc_s4(kA.x, kA.y), kloA = bc_s4(kA.z, kA.w);
            const short4v khiB = bc_s4(kB.x, kB.y), kloB = bc_s4(kB.z, kB.w);
            const short8v vt8  = __builtin_bit_cast(short8v, vv);

            #pragma unroll
            for (int f = 0; f < 2; ++f) {
                // tile A scores: keys c*128 + tp*32 + 8g + r
                const float2 a01 = __half22float2(__builtin_bit_cast(__half2, bb[f][tp].x));
                const float2 a23 = __half22float2(__builtin_bit_cast(__half2, bb[f][tp].y));
                float4v sA; sA[0] = a01.x; sA[1] = a01.y; sA[2] = a23.x; sA[3] = a23.y;
                sA = mfma16(khiA, qh[f], sA);
                sA = mfma16(kloA, qh[f], sA);
                sA = mfma16(khiA, ql[f], sA);
                // tile B scores: keys c*128 + tp*32 + 8g + 4 + r
                const float2 b01 = __half22float2(__builtin_bit_cast(__half2, bb[f][tp].z));
                const float2 b23 = __half22float2(__builtin_bit_cast(__half2, bb[f][tp].w));
                float4v sB; sB[0] = b01.x; sB[1] = b01.y; sB[2] = b23.x; sB[3] = b23.y;
                sB = mfma16(khiB, qh[f], sB);
                sB = mfma16(kloB, qh[f], sB);
                sB = mfma16(khiB, ql[f], sB);

                const float pA0 = fast_exp2(sA[0]), pA1 = fast_exp2(sA[1]);
                const float pA2 = fast_exp2(sA[2]), pA3 = fast_exp2(sA[3]);
                const float pB0 = fast_exp2(sB[0]), pB1 = fast_exp2(sB[1]);
                const float pB2 = fast_exp2(sB[2]), pB3 = fast_exp2(sB[3]);

                // K=32 A-frag: [pA0..3, pB0..3] == keys 8g..8g+7 (k = quad*8+j)
                uint4 pu;
                pu.x = pk_bf16(pA0, pA1);
                pu.y = pk_bf16(pA2, pA3);
                pu.z = pk_bf16(pB0, pB1);
                pu.w = pk_bf16(pB2, pB3);
                const short8v pf8 = __builtin_bit_cast(short8v, pu);

                acc[f]  = mfma32(pf8, vt8,  acc[f]);    // O += P*V   (32 keys)
                accl[f] = mfma32(pf8, ones8, accl[f]);  // l += sum_k P
            }
        }

        if (c < NCH - 1) {
            char* s = smem[cur ^ 1];
            *(uint4*)(s + (tid >> 2) * KHL_STRIDE + (tid & 3) * 16) = st0;
            const int e = tid + 256;
            *(uint4*)(s + (e >> 2) * KHL_STRIDE + (e & 3) * 16) = st1;
            *(uint4*)(s + KHL_CH + (tid >> 4) * VT_STRIDE + (tid & 15) * 16) = st2;
        }
        __syncthreads();
    }

    // epilogue: accl[f][r] == l for q-row 4g+r — no cross-lane traffic
    #pragma unroll
    for (int f = 0; f < 2; ++f) {
        const size_t obase = bh * SEQ + q0 + f * 64 + wave * 16;
        #pragma unroll
        for (int r = 0; r < 4; ++r) {
            out[(obase + 4 * g + r) * DK + n] = acc[f][r] / accl[f][r];
        }
    }
}

// ---------------- Fallback: single-pass scalar kernel (no workspace) ---------
#define FTQ 256
#define FTK 32
__global__ __launch_bounds__(256, 2)
void sdpa_fallback(const float* __restrict__ Q, const float* __restrict__ K,
                   const float* __restrict__ V, const int* __restrict__ mask,
                   const float* __restrict__ bias, float* __restrict__ out) {
    __shared__ float Ks[FTK][DK];
    __shared__ float Vs[FTK][DK];
    __shared__ float Bsf[FTQ][FTK + 1];

    const int tid = threadIdx.x;
    const int blk = blockIdx.x;
    const int h   = blk & (NHEAD - 1);
    const int qt  = (blk >> 4) & 3;
    const int b   = blk >> 6;
    const int q0  = qt * FTQ;
    const float qscale = 0.25f * LOG2E;
    const size_t bh = (size_t)b * NHEAD + h;

    float Qr[DK];
    {
        const float4* q4 = (const float4*)(Q + (bh * SEQ + q0 + tid) * DK);
        #pragma unroll
        for (int i = 0; i < 4; ++i) {
            float4 v = q4[i];
            Qr[4*i+0] = v.x * qscale; Qr[4*i+1] = v.y * qscale;
            Qr[4*i+2] = v.z * qscale; Qr[4*i+3] = v.w * qscale;
        }
    }
    float acc[DK];
    #pragma unroll
    for (int d = 0; d < DK; ++d) acc[d] = 0.0f;
    float l = 0.0f;

    const float* Kbase = K + bh * SEQ * DK;
    const float* Vbase = V + bh * SEQ * DK;
    const float* Bbase = bias + ((size_t)b * SEQ + q0) * SEQ;
    const int*   Mbase = mask + ((size_t)b * SEQ + q0) * SEQ;

    for (int t = 0; t < SEQ / FTK; ++t) {
        const int k0 = t * FTK;
        if (tid < 128) {
            float4 kv = ((const float4*)(Kbase + (size_t)k0 * DK))[tid];
            float4 vv = ((const float4*)(Vbase + (size_t)k0 * DK))[tid];
            ((float4*)&Ks[0][0])[tid] = kv;
            ((float4*)&Vs[0][0])[tid] = vv;
        }
        #pragma unroll
        for (int i = 0; i < 8; ++i) {
            int e4 = tid + i * 256, row = e4 >> 3, c4 = e4 & 7;
            const float4 bv = *(const float4*)(Bbase + (size_t)row * SEQ + k0 + c4 * 4);
            const int4   mv = *(const int4*)  (Mbase + (size_t)row * SEQ + k0 + c4 * 4);
            float* dst = &Bsf[row][c4 * 4];
            dst[0] = mv.x ? -1e9f : bv.x * LOG2E;
            dst[1] = mv.y ? -1e9f : bv.y * LOG2E;
            dst[2] = mv.z ? -1e9f : bv.z * LOG2E;
            dst[3] = mv.w ? -1e9f : bv.w * LOG2E;
        }
        __syncthreads();
        #pragma unroll 4
        for (int kk = 0; kk < FTK; ++kk) {
            float s = Bsf[tid][kk];
            const float4 k0v = *(const float4*)&Ks[kk][0];
            const float4 k1v = *(const float4*)&Ks[kk][4];
            const float4 k2v = *(const float4*)&Ks[kk][8];
            const float4 k3v = *(const float4*)&Ks[kk][12];
            s = fmaf(Qr[0],  k0v.x, s); s = fmaf(Qr[1],  k0v.y, s);
            s = fmaf(Qr[2],  k0v.z, s); s = fmaf(Qr[3],  k0v.w, s);
            s = fmaf(Qr[4],  k1v.x, s); s = fmaf(Qr[5],  k1v.y, s);
            s = fmaf(Qr[6],  k1v.z, s); s = fmaf(Qr[7],  k1v.w, s);
            s = fmaf(Qr[8],  k2v.x, s); s = fmaf(Qr[9],  k2v.y, s);
            s = fmaf(Qr[10], k2v.z, s); s = fmaf(Qr[11], k2v.w, s);
            s = fmaf(Qr[12], k3v.x, s); s = fmaf(Qr[13], k3v.y, s);
            s = fmaf(Qr[14], k3v.z, s); s = fmaf(Qr[15], k3v.w, s);
            float p = fast_exp2(s);
            l += p;
            const float4 v0 = *(const float4*)&Vs[kk][0];
            const float4 v1 = *(const float4*)&Vs[kk][4];
            const float4 v2 = *(const float4*)&Vs[kk][8];
            const float4 v3 = *(const float4*)&Vs[kk][12];
            acc[0]  = fmaf(p, v0.x, acc[0]);  acc[1]  = fmaf(p, v0.y, acc[1]);
            acc[2]  = fmaf(p, v0.z, acc[2]);  acc[3]  = fmaf(p, v0.w, acc[3]);
            acc[4]  = fmaf(p, v1.x, acc[4]);  acc[5]  = fmaf(p, v1.y, acc[5]);
            acc[6]  = fmaf(p, v1.z, acc[6]);  acc[7]  = fmaf(p, v1.w, acc[7]);
            acc[8]  = fmaf(p, v2.x, acc[8]);  acc[9]  = fmaf(p, v2.y, acc[9]);
            acc[10] = fmaf(p, v2.z, acc[10]); acc[11] = fmaf(p, v2.w, acc[11]);
            acc[12] = fmaf(p, v3.x, acc[12]); acc[13] = fmaf(p, v3.y, acc[13]);
            acc[14] = fmaf(p, v3.z, acc[14]); acc[15] = fmaf(p, v3.w, acc[15]);
        }
        __syncthreads();
    }
    const float inv = 1.0f / l;
    float4* o4 = (float4*)(out + (bh * SEQ + q0 + tid) * DK);
    #pragma unroll
    for (int i = 0; i < 4; ++i) {
        float4 v;
        v.x = acc[4*i+0] * inv; v.y = acc[4*i+1] * inv;
        v.z = acc[4*i+2] * inv; v.w = acc[4*i+3] * inv;
        o4[i] = v;
    }
}

extern "C" void kernel_launch(void* const* d_in, const int* in_sizes, int n_in,
                              void* d_out, int out_size, void* d_ws, size_t ws_size,
                              hipStream_t stream) {
    const float* Q    = (const float*)d_in[0];
    const float* K    = (const float*)d_in[1];
    const float* V    = (const float*)d_in[2];
    const int*   mask = (const int*)  d_in[3];
    const float* bias = (const float*)d_in[4];
    float* out = (float*)d_out;

    const size_t nKeys    = (size_t)NBATCH * NHEAD * SEQ;      // 131072
    const size_t khlBytes = nKeys * 64;                        // 8.39 MB
    const size_t vtBytes  = nKeys * DK * sizeof(short);        // 4.19 MB
    const size_t bpBytes  = (size_t)NBATCH * SEQ * SEQ * 2;    // 16.8 MB
    const size_t need     = khlBytes + vtBytes + bpBytes;      // 29.4 MB

    if (ws_size >= need) {
        char* w = (char*)d_ws;
        uint4* KHL   = (uint4*)(w);
        short* Vt    = (short*)(w + khlBytes);
        uint4* biasp = (uint4*)(w + khlBytes + vtBytes);

        prep_all<<<3072, 256, 0, stream>>>(K, V, mask, bias, KHL, Vt, biasp);
        sdpa_flash<<<1024, 256, 0, stream>>>(Q, KHL, Vt, biasp, out);
    } else {
        sdpa_fallback<<<NBATCH * NHEAD * (SEQ / FTQ), FTQ, 0, stream>>>(Q, K, V, mask, bias, out);
    }
}

// Round 10
// 154.985 us; speedup vs baseline: 1.2922x; 1.0789x over previous
//
#include <hip/hip_runtime.h>
#include <hip/hip_fp16.h>
#include <math.h>

#define SEQ    1024
#define DK     16
#define NHEAD  16
#define NBATCH 8
#define LOG2E  1.4426950408889634f

#define CH     128                       // keys per LDS chunk
#define NCH    (SEQ / CH)                // 8 chunks
#define KHI_STRIDE 40                    // LDS bytes per key row (32 data + 8 pad)
#define VT_STRIDE  272                   // LDS bytes per d row   (256 data + 16 pad)
#define KHI_CH (CH * KHI_STRIDE)         // 5120 B
#define VT_CH  (DK * VT_STRIDE)          // 4352 B
#define BUF_SZ (KHI_CH + VT_CH)          // 9472 B per buffer (x2 = 18.9 KB)

typedef __attribute__((ext_vector_type(4))) short  short4v;
typedef __attribute__((ext_vector_type(8))) short  short8v;
typedef __attribute__((ext_vector_type(2))) short  short2v;
typedef __attribute__((ext_vector_type(4))) float  float4v;
typedef __attribute__((ext_vector_type(2))) unsigned int uint2v;

static __device__ __forceinline__ float fast_exp2(float x) {
#if __has_builtin(__builtin_amdgcn_exp2f)
    return __builtin_amdgcn_exp2f(x);
#else
    return exp2f(x);
#endif
}

static __device__ __forceinline__ float4v mfma16(short4v a, short4v b, float4v c) {
#if __has_builtin(__builtin_amdgcn_mfma_f32_16x16x16bf16_1k)
    return __builtin_amdgcn_mfma_f32_16x16x16bf16_1k(a, b, c, 0, 0, 0);
#else
    float4v d = c;
    asm volatile("v_mfma_f32_16x16x16_bf16 %0, %1, %2, %0" : "+v"(d) : "v"(a), "v"(b));
    return d;
#endif
}

// K=32 MFMA: A/B = 8 bf16/lane (k = quad*8 + j). Fallback: two K=16 halves.
static __device__ __forceinline__ float4v mfma32(short8v a, short8v b, float4v c) {
#if __has_builtin(__builtin_amdgcn_mfma_f32_16x16x32_bf16)
    return __builtin_amdgcn_mfma_f32_16x16x32_bf16(a, b, c, 0, 0, 0);
#else
    short4v a0 = {a[0], a[1], a[2], a[3]}, a1 = {a[4], a[5], a[6], a[7]};
    short4v b0 = {b[0], b[1], b[2], b[3]}, b1 = {b[4], b[5], b[6], b[7]};
    c = mfma16(a0, b0, c);
    return mfma16(a1, b1, c);
#endif
}

static __device__ __forceinline__ unsigned bf16_rne(float x) {
    unsigned u = __float_as_uint(x);
    return (u + 0x7FFFu + ((u >> 16) & 1u)) >> 16;
}
static __device__ __forceinline__ float bf16_to_f(unsigned b) {
    return __uint_as_float(b << 16);
}
static __device__ __forceinline__ unsigned pk_bf16(float a, float b) {
#if __has_builtin(__builtin_amdgcn_cvt_pk_bf16_f32)
    short2v r = __builtin_amdgcn_cvt_pk_bf16_f32(a, b);
    return __builtin_bit_cast(unsigned, r);
#else
    return bf16_rne(a) | (bf16_rne(b) << 16);
#endif
}
static __device__ __forceinline__ short4v bc_s4(unsigned lo, unsigned hi) {
    uint2v u; u.x = lo; u.y = hi;
    return __builtin_bit_cast(short4v, u);
}
static __device__ __forceinline__ unsigned h2pack(int m0, float b0, int m1, float b1) {
    const __half2 a = __floats2half2_rn(m0 ? -60000.f : b0 * LOG2E,
                                        m1 ? -60000.f : b1 * LOG2E);
    return __builtin_bit_cast(unsigned, a);
}

// ---------------- Prep (one kernel, 3 jobs by block range) -------------------
// [0,2048):     bias+mask -> biasp fp16 fragment-major (64q x 64k per block)
// [2048,2560):  K -> Khi bf16 (plain rounding, 32 B per key row)
// [2560,3072):  V -> Vt bf16 [B*H][d][s]
__global__ __launch_bounds__(256)
void prep_all(const float* __restrict__ K, const float* __restrict__ V,
              const int* __restrict__ mask, const float* __restrict__ bias,
              uint2* __restrict__ KHI, short* __restrict__ Vt,
              uint4* __restrict__ biasp) {
    const int blk = blockIdx.x;
    const int t   = threadIdx.x;
    if (blk < 2048) {
        __shared__ uint4 BsT[64][9];
        const int b    = blk >> 8;
        const int qt64 = (blk >> 4) & 15;
        const int c    = (blk >> 1) & 7;
        const int half = blk & 1;
        const int kb   = c * 128 + half * 64;
        #pragma unroll
        for (int i = 0; i < 4; ++i) {
            const int idx = t + i * 256;                 // 0..1023
            const int row = idx >> 4;                    // q-local 0..63
            const int c4  = idx & 15;                    // float4 col in 64-k window
            const size_t ga = ((size_t)b * SEQ + qt64 * 64 + row) * SEQ + kb + c4 * 4;
            const float4 bv = *(const float4*)(bias + ga);
            const int4   mv = *(const int4*)(mask + ga);
            uint2 u;
            u.x = h2pack(mv.x, bv.x, mv.y, bv.y);
            u.y = h2pack(mv.z, bv.z, mv.w, bv.w);
            const int jj = c4 >> 1;
            ((uint2*)&BsT[row][jj ^ (row & 7)])[c4 & 1] = u;
        }
        __syncthreads();
        const int w = t >> 6, lane = t & 63, n = lane & 15, g = lane >> 4;
        const int row = w * 16 + n;
        #pragma unroll
        for (int tpl = 0; tpl < 2; ++tpl) {
            const int tp = half * 2 + tpl;
            const int jj = tpl * 4 + g;
            const uint4 v = BsT[row][jj ^ (row & 7)];
            const size_t ob = ((((size_t)(b * 16 + qt64) * 4 + w) * 8 + c) * 4 + tp) * 64 + lane;
            biasp[ob] = v;
        }
    } else if (blk < 2560) {
        const int base = (blk - 2048) * 1024;
        #pragma unroll
        for (int i = 0; i < 4; ++i) {
            const int i4 = base + t + i * 256;           // float4 index into K
            const float4 k = ((const float4*)K)[i4];
            uint2 o;
            o.x = pk_bf16(k.x, k.y);
            o.y = pk_bf16(k.z, k.w);
            KHI[i4] = o;
        }
    } else {
        __shared__ float Vs[64][17];
        const int vb = blk - 2560;                       // 0..511
        const int bh = vb >> 2;
        const int qq = vb & 3;
        #pragma unroll
        for (int st = 0; st < 4; ++st) {
            const int s0 = qq * 256 + st * 64;
            {
                const int row = t >> 2, c4 = t & 3;
                const float4 v = ((const float4*)V)[((size_t)bh * SEQ + s0 + row) * 4 + c4];
                Vs[row][c4 * 4 + 0] = v.x; Vs[row][c4 * 4 + 1] = v.y;
                Vs[row][c4 * 4 + 2] = v.z; Vs[row][c4 * 4 + 3] = v.w;
            }
            __syncthreads();
            const int d = t >> 4, sg = t & 15;
            short4v o;
            #pragma unroll
            for (int i = 0; i < 4; ++i) o[i] = (short)bf16_rne(Vs[sg * 4 + i][d]);
            ((short4v*)Vt)[(((size_t)bh * DK + d) * SEQ + s0) / 4 + sg] = o;
            __syncthreads();
        }
    }
}

// ---------------- Flash pass ------------------------------------------------
// 1024 blocks, blockIdx%8 == b (XCD = batch), 128 q/block, 2 frags/wave,
// CH=128 dbuf LDS. K bf16-rounded; Q kept exact via hi/lo -> QK = 2 MFMAs.
// Per tile-pair-frag: 4 QK MFMA(K=16) + PV + ones-l (K=32) = 6 MFMAs.
__global__ __launch_bounds__(256, 4)
void sdpa_flash(const float* __restrict__ Q, const uint2* __restrict__ KHI,
                const short* __restrict__ Vt, const uint4* __restrict__ biasp,
                float* __restrict__ out) {
    __shared__ __align__(16) char smem[2][BUF_SZ];

    const int tid  = threadIdx.x;
    const int wave = tid >> 6;
    const int lane = tid & 63;
    const int n    = lane & 15;
    const int g    = lane >> 4;
    const int permn = ((n >> 2) << 3) | (n & 3);   // tile-pair key permutation

    const int b  = blockIdx.x & 7;                 // XCD = batch
    const int j  = blockIdx.x >> 3;                // 0..127
    const int qt = j & 7;
    const int h  = j >> 3;                         // 0..15
    const int q0 = qt * 128;

    const size_t bh = (size_t)b * NHEAD + h;

    // 2 q-frags: q = q0 + f*64 + wave*16 + n
    short4v qh[2], ql[2];
    size_t  bfbase[2];
    #pragma unroll
    for (int f = 0; f < 2; ++f) {
        const int qrow = q0 + f * 64 + wave * 16 + n;
        const float4 qv = *(const float4*)(Q + (bh * SEQ + qrow) * DK + g * 4);
        const float qsc = 0.25f * LOG2E;
        const float v[4] = {qv.x * qsc, qv.y * qsc, qv.z * qsc, qv.w * qsc};
        #pragma unroll
        for (int e = 0; e < 4; ++e) {
            const unsigned hu = bf16_rne(v[e]);
            qh[f][e] = (short)hu;
            ql[f][e] = (short)bf16_rne(v[e] - bf16_to_f(hu));
        }
        bfbase[f] = (((size_t)(b * 16 + qt * 2 + f) * 4 + wave) * 32) * 64 + lane;
    }

    const uint4* KHIh = (const uint4*)(KHI + bh * SEQ * 4); // 2 uint4 per key row
    const uint4* VtH  = (const uint4*)(Vt + bh * DK * SEQ);

    float4v acc[2], accl[2];
    acc[0]  = (float4v){0.f, 0.f, 0.f, 0.f};
    acc[1]  = (float4v){0.f, 0.f, 0.f, 0.f};
    accl[0] = (float4v){0.f, 0.f, 0.f, 0.f};
    accl[1] = (float4v){0.f, 0.f, 0.f, 0.f};
    const short8v ones8 = {(short)0x3F80, (short)0x3F80, (short)0x3F80, (short)0x3F80,
                           (short)0x3F80, (short)0x3F80, (short)0x3F80, (short)0x3F80};

    // staging: K chunk = 256 uint4 (key = e>>1, half-row = e&1); V = 256 uint4
    uint4 st0, st2;
    {
        st0 = KHIh[tid];
        st2 = VtH[(tid >> 4) * 128 + (tid & 15)];
        char* s = smem[0];
        *(uint4*)(s + (tid >> 1) * KHI_STRIDE + (tid & 1) * 16) = st0;
        *(uint4*)(s + KHI_CH + (tid >> 4) * VT_STRIDE + (tid & 15) * 16) = st2;
    }
    __syncthreads();

    for (int c = 0; c < NCH; ++c) {
        const int cur = c & 1;
        if (c < NCH - 1) {
            st0 = KHIh[(c + 1) * 256 + tid];
            st2 = VtH[(tid >> 4) * 128 + (c + 1) * 16 + (tid & 15)];
        }
        uint4 bb[2][4];
        #pragma unroll
        for (int f = 0; f < 2; ++f)
            #pragma unroll
            for (int tp = 0; tp < 4; ++tp)
                bb[f][tp] = biasp[bfbase[f] + (size_t)(c * 4 + tp) * 64];

        const char* khl = smem[cur];
        const char* vtl = smem[cur] + KHI_CH;

        #pragma unroll
        for (int tp = 0; tp < 4; ++tp) {
            const int rowA = tp * 32 + permn;
            const uint2 kAu = *(const uint2*)(khl + rowA * KHI_STRIDE + g * 8);
            const uint2 kBu = *(const uint2*)(khl + (rowA + 4) * KHI_STRIDE + g * 8);
            const uint4 vv  = *(const uint4*)(vtl + n * VT_STRIDE + tp * 64 + g * 16);
            const short4v khiA = bc_s4(kAu.x, kAu.y);
            const short4v khiB = bc_s4(kBu.x, kBu.y);
            const short8v vt8  = __builtin_bit_cast(short8v, vv);

            #pragma unroll
            for (int f = 0; f < 2; ++f) {
                // tile A scores: keys c*128 + tp*32 + 8g + r
                const float2 a01 = __half22float2(__builtin_bit_cast(__half2, bb[f][tp].x));
                const float2 a23 = __half22float2(__builtin_bit_cast(__half2, bb[f][tp].y));
                float4v sA; sA[0] = a01.x; sA[1] = a01.y; sA[2] = a23.x; sA[3] = a23.y;
                sA = mfma16(khiA, qh[f], sA);
                sA = mfma16(khiA, ql[f], sA);
                // tile B scores: keys c*128 + tp*32 + 8g + 4 + r
                const float2 b01 = __half22float2(__builtin_bit_cast(__half2, bb[f][tp].z));
                const float2 b23 = __half22float2(__builtin_bit_cast(__half2, bb[f][tp].w));
                float4v sB; sB[0] = b01.x; sB[1] = b01.y; sB[2] = b23.x; sB[3] = b23.y;
                sB = mfma16(khiB, qh[f], sB);
                sB = mfma16(khiB, ql[f], sB);

                const float pA0 = fast_exp2(sA[0]), pA1 = fast_exp2(sA[1]);
                const float pA2 = fast_exp2(sA[2]), pA3 = fast_exp2(sA[3]);
                const float pB0 = fast_exp2(sB[0]), pB1 = fast_exp2(sB[1]);
                const float pB2 = fast_exp2(sB[2]), pB3 = fast_exp2(sB[3]);

                // K=32 A-frag: [pA0..3, pB0..3] == keys 8g..8g+7 (k = quad*8+j)
                uint4 pu;
                pu.x = pk_bf16(pA0, pA1);
                pu.y = pk_bf16(pA2, pA3);
                pu.z = pk_bf16(pB0, pB1);
                pu.w = pk_bf16(pB2, pB3);
                const short8v pf8 = __builtin_bit_cast(short8v, pu);

                acc[f]  = mfma32(pf8, vt8,  acc[f]);    // O += P*V   (32 keys)
                accl[f] = mfma32(pf8, ones8, accl[f]);  // l += sum_k P
            }
        }

        if (c < NCH - 1) {
            char* s = smem[cur ^ 1];
            *(uint4*)(s + (tid >> 1) * KHI_STRIDE + (tid & 1) * 16) = st0;
            *(uint4*)(s + KHI_CH + (tid >> 4) * VT_STRIDE + (tid & 15) * 16) = st2;
        }
        __syncthreads();
    }

    // epilogue: accl[f][r] == l for q-row 4g+r — no cross-lane traffic
    #pragma unroll
    for (int f = 0; f < 2; ++f) {
        const size_t obase = bh * SEQ + q0 + f * 64 + wave * 16;
        #pragma unroll
        for (int r = 0; r < 4; ++r) {
            out[(obase + 4 * g + r) * DK + n] = acc[f][r] / accl[f][r];
        }
    }
}

// ---------------- Fallback: single-pass scalar kernel (no workspace) ---------
#define FTQ 256
#define FTK 32
__global__ __launch_bounds__(256, 2)
void sdpa_fallback(const float* __restrict__ Q, const float* __restrict__ K,
                   const float* __restrict__ V, const int* __restrict__ mask,
                   const float* __restrict__ bias, float* __restrict__ out) {
    __shared__ float Ks[FTK][DK];
    __shared__ float Vs[FTK][DK];
    __shared__ float Bsf[FTQ][FTK + 1];

    const int tid = threadIdx.x;
    const int blk = blockIdx.x;
    const int h   = blk & (NHEAD - 1);
    const int qt  = (blk >> 4) & 3;
    const int b   = blk >> 6;
    const int q0  = qt * FTQ;
    const float qscale = 0.25f * LOG2E;
    const size_t bh = (size_t)b * NHEAD + h;

    float Qr[DK];
    {
        const float4* q4 = (const float4*)(Q + (bh * SEQ + q0 + tid) * DK);
        #pragma unroll
        for (int i = 0; i < 4; ++i) {
            float4 v = q4[i];
            Qr[4*i+0] = v.x * qscale; Qr[4*i+1] = v.y * qscale;
            Qr[4*i+2] = v.z * qscale; Qr[4*i+3] = v.w * qscale;
        }
    }
    float acc[DK];
    #pragma unroll
    for (int d = 0; d < DK; ++d) acc[d] = 0.0f;
    float l = 0.0f;

    const float* Kbase = K + bh * SEQ * DK;
    const float* Vbase = V + bh * SEQ * DK;
    const float* Bbase = bias + ((size_t)b * SEQ + q0) * SEQ;
    const int*   Mbase = mask + ((size_t)b * SEQ + q0) * SEQ;

    for (int t = 0; t < SEQ / FTK; ++t) {
        const int k0 = t * FTK;
        if (tid < 128) {
            float4 kv = ((const float4*)(Kbase + (size_t)k0 * DK))[tid];
            float4 vv = ((const float4*)(Vbase + (size_t)k0 * DK))[tid];
            ((float4*)&Ks[0][0])[tid] = kv;
            ((float4*)&Vs[0][0])[tid] = vv;
        }
        #pragma unroll
        for (int i = 0; i < 8; ++i) {
            int e4 = tid + i * 256, row = e4 >> 3, c4 = e4 & 7;
            const float4 bv = *(const float4*)(Bbase + (size_t)row * SEQ + k0 + c4 * 4);
            const int4   mv = *(const int4*)  (Mbase + (size_t)row * SEQ + k0 + c4 * 4);
            float* dst = &Bsf[row][c4 * 4];
            dst[0] = mv.x ? -1e9f : bv.x * LOG2E;
            dst[1] = mv.y ? -1e9f : bv.y * LOG2E;
            dst[2] = mv.z ? -1e9f : bv.z * LOG2E;
            dst[3] = mv.w ? -1e9f : bv.w * LOG2E;
        }
        __syncthreads();
        #pragma unroll 4
        for (int kk = 0; kk < FTK; ++kk) {
            float s = Bsf[tid][kk];
            const float4 k0v = *(const float4*)&Ks[kk][0];
            const float4 k1v = *(const float4*)&Ks[kk][4];
            const float4 k2v = *(const float4*)&Ks[kk][8];
            const float4 k3v = *(const float4*)&Ks[kk][12];
            s = fmaf(Qr[0],  k0v.x, s); s = fmaf(Qr[1],  k0v.y, s);
            s = fmaf(Qr[2],  k0v.z, s); s = fmaf(Qr[3],  k0v.w, s);
            s = fmaf(Qr[4],  k1v.x, s); s = fmaf(Qr[5],  k1v.y, s);
            s = fmaf(Qr[6],  k1v.z, s); s = fmaf(Qr[7],  k1v.w, s);
            s = fmaf(Qr[8],  k2v.x, s); s = fmaf(Qr[9],  k2v.y, s);
            s = fmaf(Qr[10], k2v.z, s); s = fmaf(Qr[11], k2v.w, s);
            s = fmaf(Qr[12], k3v.x, s); s = fmaf(Qr[13], k3v.y, s);
            s = fmaf(Qr[14], k3v.z, s); s = fmaf(Qr[15], k3v.w, s);
            float p = fast_exp2(s);
            l += p;
            const float4 v0 = *(const float4*)&Vs[kk][0];
            const float4 v1 = *(const float4*)&Vs[kk][4];
            const float4 v2 = *(const float4*)&Vs[kk][8];
            const float4 v3 = *(const float4*)&Vs[kk][12];
            acc[0]  = fmaf(p, v0.x, acc[0]);  acc[1]  = fmaf(p, v0.y, acc[1]);
            acc[2]  = fmaf(p, v0.z, acc[2]);  acc[3]  = fmaf(p, v0.w, acc[3]);
            acc[4]  = fmaf(p, v1.x, acc[4]);  acc[5]  = fmaf(p, v1.y, acc[5]);
            acc[6]  = fmaf(p, v1.z, acc[6]);  acc[7]  = fmaf(p, v1.w, acc[7]);
            acc[8]  = fmaf(p, v2.x, acc[8]);  acc[9]  = fmaf(p, v2.y, acc[9]);
            acc[10] = fmaf(p, v2.z, acc[10]); acc[11] = fmaf(p, v2.w, acc[11]);
            acc[12] = fmaf(p, v3.x, acc[12]); acc[13] = fmaf(p, v3.y, acc[13]);
            acc[14] = fmaf(p, v3.z, acc[14]); acc[15] = fmaf(p, v3.w, acc[15]);
        }
        __syncthreads();
    }
    const float inv = 1.0f / l;
    float4* o4 = (float4*)(out + (bh * SEQ + q0 + tid) * DK);
    #pragma unroll
    for (int i = 0; i < 4; ++i) {
        float4 v;
        v.x = acc[4*i+0] * inv; v.y = acc[4*i+1] * inv;
        v.z = acc[4*i+2] * inv; v.w = acc[4*i+3] * inv;
        o4[i] = v;
    }
}

extern "C" void kernel_launch(void* const* d_in, const int* in_sizes, int n_in,
                              void* d_out, int out_size, void* d_ws, size_t ws_size,
                              hipStream_t stream) {
    const float* Q    = (const float*)d_in[0];
    const float* K    = (const float*)d_in[1];
    const float* V    = (const float*)d_in[2];
    const int*   mask = (const int*)  d_in[3];
    const float* bias = (const float*)d_in[4];
    float* out = (float*)d_out;

    const size_t nKeys    = (size_t)NBATCH * NHEAD * SEQ;      // 131072
    const size_t khiBytes = nKeys * 32;                        // 4.19 MB
    const size_t vtBytes  = nKeys * DK * sizeof(short);        // 4.19 MB
    const size_t bpBytes  = (size_t)NBATCH * SEQ * SEQ * 2;    // 16.8 MB
    const size_t need     = khiBytes + vtBytes + bpBytes;      // 25.2 MB

    if (ws_size >= need) {
        char* w = (char*)d_ws;
        uint2* KHI   = (uint2*)(w);
        short* Vt    = (short*)(w + khiBytes);
        uint4* biasp = (uint4*)(w + khiBytes + vtBytes);

        prep_all<<<3072, 256, 0, stream>>>(K, V, mask, bias, KHI, Vt, biasp);
        sdpa_flash<<<1024, 256, 0, stream>>>(Q, KHI, Vt, biasp, out);
    } else {
        sdpa_fallback<<<NBATCH * NHEAD * (SEQ / FTQ), FTQ, 0, stream>>>(Q, K, V, mask, bias, out);
    }
}